// Round 5
// baseline (18273.189 us; speedup 1.0000x reference)
//
#include <hip/hip_runtime.h>
#include <hip/hip_bf16.h>
#include <hip/hip_fp16.h>
#include <stdint.h>

#define B_ 128
#define S_ 512
#define E_ 256
#define H2_ 512
#define G_ 1024      // 4*E
#define DG_ 2048     // 4*H2
#define M_ (B_*S_)   // 65536

typedef float f32x4 __attribute__((ext_vector_type(4)));
typedef short s16x8 __attribute__((ext_vector_type(8)));
typedef _Float16 h16x2 __attribute__((ext_vector_type(2)));

__device__ __forceinline__ float sigm(float x){ return 1.f/(1.f+__expf(-x)); }
__device__ __forceinline__ float tanh_f(float x){ return 1.f - 2.f/(__expf(2.f*x)+1.f); }

// ---------------- fp8 e4m3fn encode/decode ----------------
__device__ __forceinline__ uint32_t enc_e4m3(float f){
  uint32_t u = __float_as_uint(f);
  uint32_t s = (u >> 24) & 0x80u;
  float af = fabsf(f);
  if (!(af > 0.f)) return s;
  if (af >= 448.f) return s | 0x7Eu;
  int ex = (int)((u >> 23) & 0xFF) - 127;
  uint32_t man = u & 0x7FFFFFu;
  int bexp = ex + 7;
  if (bexp <= 0){
    uint32_t qi = (uint32_t)rintf(af * 512.f);
    if (qi > 8u) qi = 8u;
    return s | qi;
  }
  uint32_t keep = man >> 20;
  uint32_t rest = man & 0xFFFFFu;
  const uint32_t half = 0x80000u;
  if (rest > half || (rest == half && (keep & 1u))) keep++;
  if (keep == 8u){ keep = 0u; bexp++; }
  if (bexp >= 16) return s | 0x7Eu;
  if (bexp == 15 && keep == 7u) keep = 6u; // avoid NaN encoding
  return s | ((uint32_t)bexp << 3) | keep;
}

__device__ __forceinline__ float dec_e4m3(uint32_t byte){
  uint32_t s = (byte & 0x80u) << 24;
  uint32_t e = (byte >> 3) & 0xFu;
  uint32_t m = byte & 7u;
  float v;
  if (e == 0) v = (float)m * 0.001953125f;
  else v = __uint_as_float(((e + 120u) << 23) | (m << 20));
  return __uint_as_float(__float_as_uint(v) | s);
}

__device__ __forceinline__ void fp8x4_to_f32x4(uint32_t w, float* o){
#if __has_builtin(__builtin_amdgcn_cvt_pk_f32_fp8)
  auto lo = __builtin_amdgcn_cvt_pk_f32_fp8((int)w, false);
  auto hi = __builtin_amdgcn_cvt_pk_f32_fp8((int)w, true);
  o[0]=lo[0]; o[1]=lo[1]; o[2]=hi[0]; o[3]=hi[1];
#else
  o[0]=dec_e4m3(w & 0xFFu); o[1]=dec_e4m3((w>>8)&0xFFu);
  o[2]=dec_e4m3((w>>16)&0xFFu); o[3]=dec_e4m3(w>>24);
#endif
}

__device__ __forceinline__ float dot2_f16(uint32_t a, uint32_t b, float acc){
#if __has_builtin(__builtin_amdgcn_fdot2)
  return __builtin_amdgcn_fdot2(__builtin_bit_cast(h16x2,a), __builtin_bit_cast(h16x2,b), acc, false);
#else
  __half2 ah = __builtin_bit_cast(__half2, a), bh = __builtin_bit_cast(__half2, b);
  float2 af = __half22float2(ah), bf = __half22float2(bh);
  return fmaf(af.x, bf.x, fmaf(af.y, bf.y, acc));
#endif
}

// ---------------- weight prep ----------------
__global__ __launch_bounds__(512) void k_prep_enc(
    const float* __restrict__ wf, const float* __restrict__ wb,
    const float* __restrict__ bihf, const float* __restrict__ bhhf,
    const float* __restrict__ bihb, const float* __restrict__ bhhb,
    ushort* __restrict__ Wenc, float* __restrict__ bsum){
  int n = blockIdx.x, d = threadIdx.x;
  const float* src = (n < G_) ? (wf + (size_t)n*H2_) : (wb + (size_t)(n-G_)*H2_);
  __hip_bfloat16 h = __float2bfloat16(src[d]);
  Wenc[(size_t)n*H2_ + d] = __builtin_bit_cast(ushort, h);
  if (d == 0) bsum[n] = (n < G_) ? (bihf[n] + bhhf[n]) : (bihb[n-G_] + bhhb[n-G_]);
}

__global__ __launch_bounds__(256) void k_prep_whh(
    const float* __restrict__ whf, const float* __restrict__ whb, uint8_t* __restrict__ whh8){
  int r = blockIdx.x; int d = threadIdx.x;
  int dir = r >> 10, g = r & 1023;
  float v = dir ? whb[(size_t)g*E_ + d] : whf[(size_t)g*E_ + d];
  whh8[((size_t)dir*G_ + g)*E_ + d] = (uint8_t)enc_e4m3(v);
}

__global__ __launch_bounds__(64) void k_prep_dec(
    const float* __restrict__ wd, const float* __restrict__ bih, const float* __restrict__ bhh,
    uint4* __restrict__ wdt, float* __restrict__ bsumd){
  int row = blockIdx.x, u = threadIdx.x; // u in [0,64)
  const float* src = wd + (size_t)row*H2_ + u*8;
  union { _Float16 h[8]; uint4 q; } pk;
  #pragma unroll
  for (int i=0;i<8;i++) pk.h[i] = (_Float16)src[i];
  wdt[(size_t)u*DG_ + row] = pk.q;
  if (u == 0) bsumd[row] = bih[row] + bhh[row];
}

// ---------------- input stats ----------------
__global__ __launch_bounds__(512) void k_xstat(
    const float* __restrict__ X, float* __restrict__ SX, float* __restrict__ SX2){
  int b = blockIdx.x, d = threadIdx.x;
  const float* xb = X + (size_t)b*S_*H2_;
  float s=0.f, s2=0.f;
  for (int t=0;t<S_;++t){ float v = xb[(size_t)t*H2_ + d]; s += v; s2 = fmaf(v,v,s2); }
  SX[(size_t)b*H2_+d]=s; SX2[(size_t)b*H2_+d]=s2;
}

// ---------------- pre-GEMM: pre[m][n] = X[m][:] . Wenc[n][:] + bsum[n] ----------------
__global__ __launch_bounds__(256) void k_gemm_pre(
    const float* __restrict__ X, const ushort* __restrict__ Wenc,
    const float* __restrict__ bsum, __hip_bfloat16* __restrict__ pre){
  __shared__ ushort As[128][64];
  __shared__ ushort Bs[128][64];
  int n0 = blockIdx.x * 128, m0 = blockIdx.y * 128;
  int tid = threadIdx.x, lane = tid & 63, wid = tid >> 6;
  int wr = wid >> 1, wc = wid & 1;
  f32x4 acc[4][4] = {};
  for (int kt=0; kt<8; ++kt){
    int k0 = kt*64;
    #pragma unroll
    for (int it=0; it<4; ++it){
      int slot = tid + it*256;
      int r = slot >> 3, c8 = (slot & 7)*8;
      const float* ap = X + (size_t)(m0+r)*512 + k0 + c8;
      float4 a0 = *(const float4*)ap;
      float4 a1 = *(const float4*)(ap+4);
      union { __hip_bfloat16 h[8]; uint4 q; } pk;
      pk.h[0]=__float2bfloat16(a0.x); pk.h[1]=__float2bfloat16(a0.y);
      pk.h[2]=__float2bfloat16(a0.z); pk.h[3]=__float2bfloat16(a0.w);
      pk.h[4]=__float2bfloat16(a1.x); pk.h[5]=__float2bfloat16(a1.y);
      pk.h[6]=__float2bfloat16(a1.z); pk.h[7]=__float2bfloat16(a1.w);
      *(uint4*)&As[r][c8] = pk.q;
      *(uint4*)&Bs[r][c8] = *(const uint4*)(Wenc + (size_t)(n0+r)*512 + k0 + c8);
    }
    __syncthreads();
    #pragma unroll
    for (int kk=0; kk<2; ++kk){
      int krow = kk*32 + (lane>>4)*8;
      s16x8 af[4], bf[4];
      #pragma unroll
      for (int mi=0;mi<4;mi++) af[mi] = *(const s16x8*)&As[wr*64+mi*16+(lane&15)][krow];
      #pragma unroll
      for (int ni=0;ni<4;ni++) bf[ni] = *(const s16x8*)&Bs[wc*64+ni*16+(lane&15)][krow];
      #pragma unroll
      for (int mi=0;mi<4;mi++){
        #pragma unroll
        for (int ni=0;ni<4;ni++)
          acc[mi][ni] = __builtin_amdgcn_mfma_f32_16x16x32_bf16(af[mi], bf[ni], acc[mi][ni], 0,0,0);
      }
    }
    __syncthreads();
  }
  #pragma unroll
  for (int ni=0; ni<4; ++ni){
    int n = n0 + wc*64 + ni*16 + (lane&15);
    float bs = bsum[n];
    #pragma unroll
    for (int mi=0; mi<4; ++mi){
      int mb = m0 + wr*64 + mi*16 + (lane>>4)*4;
      #pragma unroll
      for (int r2=0;r2<4;r2++)
        pre[(size_t)(mb+r2)*DG_ + n] = __float2bfloat16(acc[mi][ni][r2] + bs);
    }
  }
}

// ---------------- encoder recurrence v5 ----------------
// 256 wgs = (dir, b), 512 threads. Thread t: jj = t>>1 (hidden unit), kh = t&1
// (k-half). Registers: gate rows i (jj), f (jj+256) over k in [kh*128,kh*128+128)
// as fp8 -> 16 named uint4 = 64 VGPRs. LDS: gate rows g,o (512..1023) as fp8,
// chunk-major wlds[u][row] (128 KB) so wave reads are 16B-consecutive
// (conflict-free); read incrementally with 1-chunk prefetch (2 uint4 live).
// Live set ~100 VGPRs < the 128 the allocator empirically gives 512-thr blocks.
__global__ __launch_bounds__(512) void k_enc_rec(
    const __hip_bfloat16* __restrict__ pre, const uint8_t* __restrict__ whh8,
    float* __restrict__ SH, float* __restrict__ x0){
  int wg = blockIdx.x;
  int dir = wg >> 7, b = wg & 127;
  int t = threadIdx.x;
  int jj = t >> 1, kh = t & 1;
  // h halves offset by 132 floats so the two broadcast addresses differ in bank
  __shared__ float hbuf[2][264];
  // wlds[u][row]: u = k-chunk (16 fp8), row 0..511 = gate rows 512..1023 (g then o)
  __shared__ uint4 wlds[16*512];   // 128 KB

  // --- stage LDS weights (g,o gates): row rr = t handles gate row 512+rr ---
  {
    const uint4* src = (const uint4*)(whh8 + ((size_t)dir*G_ + 512 + t)*E_);
    #pragma unroll
    for (int u=0; u<16; ++u) wlds[u*512 + t] = src[u];
  }
  // --- register weights (i,f gates) ---
  uint4 wi0,wi1,wi2,wi3,wi4,wi5,wi6,wi7;
  uint4 wf0,wf1,wf2,wf3,wf4,wf5,wf6,wf7;
  {
    const uint4* pi = (const uint4*)(whh8 + ((size_t)dir*G_ + jj)*E_ + kh*128);
    const uint4* pf = (const uint4*)(whh8 + ((size_t)dir*G_ + jj + 256)*E_ + kh*128);
    wi0=pi[0]; wi1=pi[1]; wi2=pi[2]; wi3=pi[3];
    wi4=pi[4]; wi5=pi[5]; wi6=pi[6]; wi7=pi[7];
    wf0=pf[0]; wf1=pf[1]; wf2=pf[2]; wf3=pf[3];
    wf4=pf[4]; wf5=pf[5]; wf6=pf[6]; wf7=pf[7];
  }
  int slot = (jj < 128) ? jj : (jj + 4);
  hbuf[0][slot] = 0.f;
  float c = 0.f, sh = 0.f;
  const __hip_bfloat16* preB = pre + ((size_t)b*S_)*DG_ + dir*G_;
  int t0 = dir ? (S_-1) : 0;
  // kh==0 lane carries pre of rows (i,f); kh==1 lane carries (g,o)
  float p0 = __bfloat162float(preB[(size_t)t0*DG_ + jj + kh*512]);
  float p1 = __bfloat162float(preB[(size_t)t0*DG_ + jj + kh*512 + 256]);
  __syncthreads();

  const uint4* wg_p = &wlds[(size_t)(kh*8)*512 + jj];         // g rows
  const uint4* wo_p = &wlds[(size_t)(kh*8)*512 + 256 + jj];   // o rows

#define WORD(IW, FW, GW, OW, HI) do { \
    float4 hv = h4[HI]; \
    float di[4], df[4], dg[4], dq[4]; \
    fp8x4_to_f32x4(IW, di); fp8x4_to_f32x4(FW, df); \
    fp8x4_to_f32x4(GW, dg); fp8x4_to_f32x4(OW, dq); \
    ai = fmaf(di[0],hv.x,ai); ai = fmaf(di[1],hv.y,ai); \
    ai = fmaf(di[2],hv.z,ai); ai = fmaf(di[3],hv.w,ai); \
    af_ = fmaf(df[0],hv.x,af_); af_ = fmaf(df[1],hv.y,af_); \
    af_ = fmaf(df[2],hv.z,af_); af_ = fmaf(df[3],hv.w,af_); \
    ag = fmaf(dg[0],hv.x,ag); ag = fmaf(dg[1],hv.y,ag); \
    ag = fmaf(dg[2],hv.z,ag); ag = fmaf(dg[3],hv.w,ag); \
    ao = fmaf(dq[0],hv.x,ao); ao = fmaf(dq[1],hv.y,ao); \
    ao = fmaf(dq[2],hv.z,ao); ao = fmaf(dq[3],hv.w,ao); \
  } while(0)

#define CHUNK(WI, WF, UU) do { \
    uint4 gc = g_nx, oc = o_nx; \
    if ((UU) < 7) { g_nx = wg_p[((UU)+1)*512]; o_nx = wo_p[((UU)+1)*512]; } \
    WORD(WI.x, WF.x, gc.x, oc.x, (UU)*4+0); \
    WORD(WI.y, WF.y, gc.y, oc.y, (UU)*4+1); \
    WORD(WI.z, WF.z, gc.z, oc.z, (UU)*4+2); \
    WORD(WI.w, WF.w, gc.w, oc.w, (UU)*4+3); \
  } while(0)

  int pbuf = 0;
  for (int s=0; s<S_; ++s){
    float ai=0.f, af_=0.f, ag=0.f, ao=0.f;
    const float4* h4 = (const float4*)(hbuf[pbuf] + kh*132);
    uint4 g_nx = wg_p[0], o_nx = wo_p[0];
    CHUNK(wi0, wf0, 0); CHUNK(wi1, wf1, 1);
    CHUNK(wi2, wf2, 2); CHUNK(wi3, wf3, 3);
    CHUNK(wi4, wf4, 4); CHUNK(wi5, wf5, 5);
    CHUNK(wi6, wf6, 6); CHUNK(wi7, wf7, 7);
    // fold pre (each lane holds 2 of the 4 gate-pre values; added once pre-shuffle)
    if (kh == 0){ ai += p0; af_ += p1; } else { ag += p0; ao += p1; }
    // prefetch next step's pre
    if (s+1 < S_){
      int tn = dir ? (S_-2-s) : (s+1);
      p0 = __bfloat162float(preB[(size_t)tn*DG_ + jj + kh*512]);
      p1 = __bfloat162float(preB[(size_t)tn*DG_ + jj + kh*512 + 256]);
    }
    // sum k-halves across the lane pair
    ai  += __shfl_xor(ai, 1);
    af_ += __shfl_xor(af_, 1);
    ag  += __shfl_xor(ag, 1);
    ao  += __shfl_xor(ao, 1);
    float cn = sigm(af_)*c + sigm(ai)*tanh_f(ag);
    float hn = sigm(ao)*tanh_f(cn);
    c = cn;
    sh += hn;
    hbuf[pbuf^1][slot] = hn;   // both lanes write identical value
    if (kh == 0 && ((dir==0 && s==S_-1) || (dir==1 && s==0)))
      x0[(size_t)b*H2_ + dir*E_ + jj] = hn;
    __syncthreads();
    pbuf ^= 1;
  }
#undef CHUNK
#undef WORD
  if (kh == 0) SH[((size_t)dir*B_ + b)*E_ + jj] = sh;
}

// ---------------- decoder + ae_loss: 128 wgs = b, 512 thr = hidden dim ----------------
#define EPS_CONV 2e-6f
__global__ __launch_bounds__(512) void k_dec(
    const float* __restrict__ X, const uint4* __restrict__ wdt,
    const float* __restrict__ bsumd, const float* __restrict__ x0,
    const float* __restrict__ SX, const float* __restrict__ SX2,
    float* __restrict__ loss_b){
  int b = blockIdx.x, j = threadIdx.x;
  __shared__ _Float16 hl[512];
  __shared__ float red[512];
  __shared__ int s_any;
  float h = x0[(size_t)b*H2_ + j];
  hl[j] = (_Float16)h;
  float bi = bsumd[j], bg = bsumd[j+1024], bo = bsumd[j+1536];
  float sxp = 0.f, x2p = 0.f, lacc = 0.f;
  const float* xb = X + (size_t)b*S_*H2_;
  int done = S_;
  __syncthreads();
  for (int s=0; s<S_; ++s){
    if (j == 0) s_any = 0;
    float ai = bi, ag = bg, ao = bo;
    const uint4* hp = (const uint4*)hl;
    const uint4* wi = wdt + j;
    const uint4* wgp = wdt + j + 1024;
    const uint4* wo = wdt + j + 1536;
    #pragma unroll 8
    for (int u=0; u<64; ++u){
      uint4 hv = hp[u];
      uint4 a = wi[(size_t)u*DG_];
      uint4 g = wgp[(size_t)u*DG_];
      uint4 o = wo[(size_t)u*DG_];
      ai = dot2_f16(a.x, hv.x, ai); ai = dot2_f16(a.y, hv.y, ai);
      ai = dot2_f16(a.z, hv.z, ai); ai = dot2_f16(a.w, hv.w, ai);
      ag = dot2_f16(g.x, hv.x, ag); ag = dot2_f16(g.y, hv.y, ag);
      ag = dot2_f16(g.z, hv.z, ag); ag = dot2_f16(g.w, hv.w, ag);
      ao = dot2_f16(o.x, hv.x, ao); ao = dot2_f16(o.y, hv.y, ao);
      ao = dot2_f16(o.z, hv.z, ao); ao = dot2_f16(o.w, hv.w, ao);
    }
    float cc = sigm(ai) * tanh_f(ag);
    float hn = sigm(ao) * tanh_f(cc);
    float xv = xb[(size_t)s*H2_ + j];
    float dd = xv - hn;
    lacc += dd*dd; sxp += xv; x2p = fmaf(xv,xv,x2p);
    float delta = fabsf(hn - h);
    h = hn;
    __syncthreads();                      // dot reads of old hl done; s_any cleared
    hl[j] = (_Float16)h;
    if (__any(delta > EPS_CONV) && (j & 63) == 0) s_any = 1;
    __syncthreads();
    if (!s_any){ done = s+1; break; }
  }
  if (done < S_){
    size_t o = (size_t)b*H2_ + j;
    float rx = SX[o] - sxp, rx2 = SX2[o] - x2p;
    float rem = (float)(S_ - done);
    lacc += rx2 - 2.f*h*rx + rem*h*h;
  }
  red[j] = lacc;
  __syncthreads();
  for (int st=256; st>0; st>>=1){
    if (j < st) red[j] += red[j+st];
    __syncthreads();
  }
  if (j == 0) loss_b[b] = red[0];
}

// ---------------- output head ----------------
__global__ __launch_bounds__(256) void k_out(
    const float* __restrict__ SX, const float* __restrict__ SH,
    const float* __restrict__ outW, const float* __restrict__ outWb,
    const float* __restrict__ loss_b, float* __restrict__ out){
  int b = blockIdx.x, o = threadIdx.x;
  __shared__ float pooled[512];
  for (int d=o; d<512; d+=256){
    float v = SX[(size_t)b*H2_ + d];
    v += (d < E_) ? SH[(size_t)b*E_ + d] : SH[(size_t)(B_ + b)*E_ + (d - E_)];
    pooled[d] = v;
  }
  __syncthreads();
  const float4* w4 = (const float4*)(outW + (size_t)o*H2_);
  const float4* p4 = (const float4*)pooled;
  float acc = outWb[o];
  #pragma unroll 16
  for (int i=0;i<128;i++){
    float4 w = w4[i], p = p4[i];
    acc = fmaf(w.x,p.x,acc); acc = fmaf(w.y,p.y,acc);
    acc = fmaf(w.z,p.z,acc); acc = fmaf(w.w,p.w,acc);
  }
  out[(size_t)b*256 + o] = acc;
  if (b == 0 && o == 0){
    float L = 0.f;
    for (int i=0;i<B_;i++) L += loss_b[i];
    out[32768] = L / 33554432.f;
  }
}

extern "C" void kernel_launch(void* const* d_in, const int* in_sizes, int n_in,
                              void* d_out, int out_size, void* d_ws, size_t ws_size,
                              hipStream_t stream) {
  const float* X     = (const float*)d_in[0];
  const float* Wihf  = (const float*)d_in[1];
  const float* Whhf  = (const float*)d_in[2];
  const float* bihf  = (const float*)d_in[3];
  const float* bhhf  = (const float*)d_in[4];
  const float* Wihb  = (const float*)d_in[5];
  const float* Whhb  = (const float*)d_in[6];
  const float* bihb  = (const float*)d_in[7];
  const float* bhhb  = (const float*)d_in[8];
  const float* Wdec  = (const float*)d_in[9];
  const float* dbih  = (const float*)d_in[10];
  const float* dbhh  = (const float*)d_in[11];
  // d_in[12..15]: attW/attW_b/attU/attU_b are mathematically dead (softmax over size-1 axis)
  const float* outW  = (const float*)d_in[16];
  const float* outWb = (const float*)d_in[17];
  float* out = (float*)d_out;

  char* ws = (char*)d_ws;
  size_t off = 0;
  auto alloc = [&](size_t bytes){ void* p = ws + off; off += (bytes + 255) & ~(size_t)255; return p; };
  __hip_bfloat16* pre  = (__hip_bfloat16*)alloc((size_t)M_*DG_*2);   // 268 MB
  ushort* Wenc         = (ushort*)alloc((size_t)DG_*H2_*2);
  float* bsum          = (float*)alloc((size_t)DG_*4);
  uint8_t* whh8        = (uint8_t*)alloc((size_t)2*G_*E_);
  uint4* wdt           = (uint4*)alloc((size_t)64*DG_*16);
  float* bsumd         = (float*)alloc((size_t)DG_*4);
  float* SX            = (float*)alloc((size_t)B_*H2_*4);
  float* SX2           = (float*)alloc((size_t)B_*H2_*4);
  float* SH            = (float*)alloc((size_t)2*B_*E_*4);
  float* x0            = (float*)alloc((size_t)B_*H2_*4);
  float* loss_b        = (float*)alloc((size_t)B_*4);

  hipLaunchKernelGGL(k_prep_enc, dim3(DG_), dim3(512), 0, stream,
                     Wihf, Wihb, bihf, bhhf, bihb, bhhb, Wenc, bsum);
  hipLaunchKernelGGL(k_prep_whh, dim3(2*G_), dim3(E_), 0, stream, Whhf, Whhb, whh8);
  hipLaunchKernelGGL(k_prep_dec, dim3(DG_), dim3(64), 0, stream, Wdec, dbih, dbhh, wdt, bsumd);
  hipLaunchKernelGGL(k_xstat, dim3(B_), dim3(H2_), 0, stream, X, SX, SX2);
  hipLaunchKernelGGL(k_gemm_pre, dim3(16, 512), dim3(256), 0, stream, X, Wenc, bsum, pre);
  hipLaunchKernelGGL(k_enc_rec, dim3(256), dim3(512), 0, stream,
                     pre, whh8, SH, x0);
  hipLaunchKernelGGL(k_dec, dim3(B_), dim3(512), 0, stream, X, wdt, bsumd, x0, SX, SX2, loss_b);
  hipLaunchKernelGGL(k_out, dim3(B_), dim3(256), 0, stream, SX, SH, outW, outWb, loss_b, out);
}